// Round 1
// baseline (60.448 us; speedup 1.0000x reference)
//
#include <hip/hip_runtime.h>

// Problem constants (fixed by the reference)
#define NUM_CH     5
#define GRID_DIM   32
#define VOX_PER_B  (GRID_DIM*GRID_DIM*GRID_DIM)   // 32768

// Gather, register-resident atoms + ballot-pruned atom loop, 4 z-voxels/thread.
// Each 256-thread block covers one full x-slice (1x32x32 voxels, gx uniform).
// Thread t: gy = t>>3 (32 rows), gz0 = (t&7)*4 (4 consecutive z per thread,
// stored as one float4 per channel). Each WAVE covers a 1x8x32 slab — the same
// slab a whole block covered in the previous version — so the per-wave ballot
// prune (exact in x, 8-row window in y, conservative z) keeps the candidate
// count at ~2.5 atoms/wave while wave count drops 4096 -> 1024 and store
// instruction count drops 4x (same bytes via dwordx4).
// Lane L holds atom L of the batch (64 atoms == wave64). Candidate mask via
// __ballot; iterate set bits with __ffsll and broadcast via v_readlane.
// Window test |g - floor(s)| <= 5  <=>  |(g+0.5) - s| <= 5.5 for non-integer
// s (degenerate integer s errs <= 0.023 < 0.0295 threshold) — same criterion
// as the previously verified kernel.
__global__ __launch_bounds__(256) void gather_kernel(
    const float* __restrict__ coords,     // [B, 64, 3]
    const int*   __restrict__ channel,    // [B, 64]
    const float* __restrict__ radius,     // [B, 64]
    float* __restrict__ out)              // [B, 5, 32, 32, 32]
{
    const int b    = blockIdx.x >> 5;                    // 32 blocks/batch
    const int gx   = blockIdx.x & 31;                    // block-uniform slice
    const int tid  = threadIdx.x;
    const int lane = tid & 63;
    const int gy   = tid >> 3;                           // 0..31
    const int gz0  = (tid & 7) << 2;                     // 0,4,...,28

    // Crop-local scaled coords: s' = (c+20)*4 + 6 - 70, voxel centers at x+0.5.
    const int a0i = (b << 6) + lane;
    const float vsx = (coords[3*a0i + 0] + 20.0f) * 4.0f - 64.0f;
    const float vsy = (coords[3*a0i + 1] + 20.0f) * 4.0f - 64.0f;
    const float vsz = (coords[3*a0i + 2] + 20.0f) * 4.0f - 64.0f;
    const float rr  = radius[a0i];
    const float vkg = -0.03125f / (rr * rr);             // -0.5 * RES^2 / r^2
    const int   vch = channel[a0i];

    const float fx  = (float)gx + 0.5f;
    const float fy  = (float)gy + 0.5f;
    const float fz0 = (float)gz0 + 0.5f;
    const float wyc = (float)((tid >> 6) << 3) + 4.0f;   // wave's y-slab center

    // Prune: exact in x (single gx), wave-local 8-row window in y (3.5+5.5),
    // conservative z (32 cols -> 15.5+5.5). Ballot is per-wave, and all lanes
    // of a wave share the same y slab, so the mask is wave-coherent.
    const bool cand = fabsf(vsx - fx) <= 5.5f &&
                      fabsf(vsy - wyc) <= 9.0f &&
                      fabsf(vsz - 16.0f) <= 21.0f;
    unsigned long long mask = __ballot(cand);

    float4 c0 = make_float4(0.f,0.f,0.f,0.f);
    float4 c1 = c0, c2 = c0, c3 = c0, c4 = c0;

    while (mask) {
        const int a = __ffsll(mask) - 1;                 // uniform (SGPR)
        mask &= mask - 1;
        const float sy = __int_as_float(__builtin_amdgcn_readlane(__float_as_int(vsy), a));
        const float dy = fy - sy;
        // x-test already exact via the prune; y per thread, z per voxel below.
        if (fabsf(dy) <= 5.5f) {
            const float sx = __int_as_float(__builtin_amdgcn_readlane(__float_as_int(vsx), a));
            const float sz = __int_as_float(__builtin_amdgcn_readlane(__float_as_int(vsz), a));
            const float kg = __int_as_float(__builtin_amdgcn_readlane(__float_as_int(vkg), a));
            const int   ch = __builtin_amdgcn_readlane(vch, a);  // uniform -> s_cmp
            const float dx  = fx - sx;
            const float b2  = dx*dx + dy*dy;
            const float dz0 = fz0 - sz;
            const float dz1 = dz0 + 1.0f;
            const float dz2 = dz0 + 2.0f;
            const float dz3 = dz0 + 3.0f;
            float v0 = __expf(kg * (b2 + dz0*dz0));
            float v1 = __expf(kg * (b2 + dz1*dz1));
            float v2 = __expf(kg * (b2 + dz2*dz2));
            float v3 = __expf(kg * (b2 + dz3*dz3));
            v0 = (fabsf(dz0) <= 5.5f) ? v0 : 0.0f;       // predicated window
            v1 = (fabsf(dz1) <= 5.5f) ? v1 : 0.0f;
            v2 = (fabsf(dz2) <= 5.5f) ? v2 : 0.0f;
            v3 = (fabsf(dz3) <= 5.5f) ? v3 : 0.0f;
            if      (ch == 0) { c0.x += v0; c0.y += v1; c0.z += v2; c0.w += v3; }
            else if (ch == 1) { c1.x += v0; c1.y += v1; c1.z += v2; c1.w += v3; }
            else if (ch == 2) { c2.x += v0; c2.y += v1; c2.z += v2; c2.w += v3; }
            else if (ch == 3) { c3.x += v0; c3.y += v1; c3.z += v2; c3.w += v3; }
            else              { c4.x += v0; c4.y += v1; c4.z += v2; c4.w += v3; }
        }
    }

    // out[b][c][gx][gy][gz0..gz0+3] — 16B-aligned, fully coalesced dwordx4.
    float* o = out + (size_t)b * NUM_CH * VOX_PER_B + (gx << 10) + (gy << 5) + gz0;
    *reinterpret_cast<float4*>(o + 0*VOX_PER_B) = c0;
    *reinterpret_cast<float4*>(o + 1*VOX_PER_B) = c1;
    *reinterpret_cast<float4*>(o + 2*VOX_PER_B) = c2;
    *reinterpret_cast<float4*>(o + 3*VOX_PER_B) = c3;
    *reinterpret_cast<float4*>(o + 4*VOX_PER_B) = c4;
}

extern "C" void kernel_launch(void* const* d_in, const int* in_sizes, int n_in,
                              void* d_out, int out_size, void* d_ws, size_t ws_size,
                              hipStream_t stream) {
    const float* coords  = (const float*)d_in[0];
    const int*   channel = (const int*)d_in[1];
    const float* radius  = (const float*)d_in[2];
    float* out = (float*)d_out;

    const int B = in_sizes[1] / 64;                      // 8
    hipLaunchKernelGGL(gather_kernel, dim3(B * 32), dim3(256), 0, stream,
                       coords, channel, radius, out);
}